// Round 5
// baseline (984.033 us; speedup 1.0000x reference)
//
#include <hip/hip_runtime.h>
#include <hip/hip_bf16.h>

#define N_NODES 50000
#define N_EDGES 600000
#define HID 128
#define HEADS 8
#define OUTC 16
#define NEG_SLOPE 0.2f
#define BN_EPS 1e-5f

typedef __attribute__((ext_vector_type(8))) short short8;
typedef __attribute__((ext_vector_type(4))) float floatx4;

__device__ __forceinline__ float bf_lo(unsigned int v) { return __uint_as_float(v << 16); }
__device__ __forceinline__ float bf_hi(unsigned int v) { return __uint_as_float(v & 0xffff0000u); }

__device__ __forceinline__ short f2bfs(float v) {
    __hip_bfloat16 b = __float2bfloat16(v);
    return *reinterpret_cast<short*>(&b);
}

// ---------------- CSR build ----------------
__global__ void k_hist(const int* __restrict__ dst, int* __restrict__ deg, int e) {
    int i = blockIdx.x * 256 + threadIdx.x;
    if (i < e) atomicAdd(&deg[dst[i]], 1);
}

__global__ void k_scan1(const int* __restrict__ deg, int* __restrict__ incl,
                        int* __restrict__ partials, int n) {
    __shared__ int sh[512];
    int i = blockIdx.x * 512 + threadIdx.x;
    int v = (i < n) ? deg[i] : 0;
    sh[threadIdx.x] = v;
    __syncthreads();
    for (int off = 1; off < 512; off <<= 1) {
        int t = (threadIdx.x >= off) ? sh[threadIdx.x - off] : 0;
        __syncthreads();
        sh[threadIdx.x] += t;
        __syncthreads();
    }
    if (i < n) incl[i] = sh[threadIdx.x];
    if (threadIdx.x == 511) partials[blockIdx.x] = sh[511];
}

__global__ void k_scan2(int* __restrict__ partials, int nb) {
    __shared__ int sh[128];
    int v = (threadIdx.x < nb) ? partials[threadIdx.x] : 0;
    sh[threadIdx.x] = v;
    __syncthreads();
    for (int off = 1; off < 128; off <<= 1) {
        int t = (threadIdx.x >= off) ? sh[threadIdx.x - off] : 0;
        __syncthreads();
        sh[threadIdx.x] += t;
        __syncthreads();
    }
    if (threadIdx.x < nb) partials[threadIdx.x] = sh[threadIdx.x] - v;  // exclusive
}

__global__ void k_scan3(const int* __restrict__ deg, const int* __restrict__ incl,
                        const int* __restrict__ partials, int* __restrict__ row_ptr,
                        int* __restrict__ cursor, int n, int e_total) {
    int i = blockIdx.x * 512 + threadIdx.x;
    if (i < n) {
        int rp = incl[i] - deg[i] + partials[blockIdx.x];
        row_ptr[i] = rp;
        cursor[i] = rp;
    }
    if (i == 0) row_ptr[n] = e_total;
}

__global__ void k_scatter(const int* __restrict__ src, const int* __restrict__ dst,
                          int* __restrict__ cursor, int* __restrict__ col_src, int e) {
    int i = blockIdx.x * 256 + threadIdx.x;
    if (i < e) {
        int d = dst[i];
        int p = atomicAdd(&cursor[d], 1);
        col_src[p] = src[i];
    }
}

// ---------------- W fp32 -> bf16 transpose (Wt[l][n][k] = W[l][k][n]) ----------------
__global__ void k_wt(const float* __restrict__ W, __hip_bfloat16* __restrict__ Wt) {
    int i = blockIdx.x * 256 + threadIdx.x;   // 3*16384 total
    if (i >= 3 * 16384) return;
    int l = i >> 14, r = i & 16383, n = r >> 7, k = r & 127;
    Wt[i] = __float2bfloat16(W[l * 16384 + k * 128 + n]);
}

// -------- WA[l][j][k] = sum_c W[l][k][(j&7)*16+c] * att_j[c]  (j<8: src, j>=8: dst) ----
__global__ void k_wa(const float* __restrict__ W, const float* __restrict__ asrc,
                     const float* __restrict__ adst, __hip_bfloat16* __restrict__ WAT) {
    int i = blockIdx.x * 256 + threadIdx.x;   // 3*16*128 = 6144
    if (i >= 3 * 2048) return;
    int l = i >> 11, r = i & 2047, j = r >> 7, k = r & 127;
    const float* att = (j < 8) ? (asrc + l * 128 + j * 16) : (adst + l * 128 + (j - 8) * 16);
    const float* Wrow = W + l * 16384 + k * 128 + (j & 7) * 16;
    float sum = 0.f;
#pragma unroll
    for (int c = 0; c < 16; c++) sum += Wrow[c] * att[c];
    WAT[i] = __float2bfloat16(sum);
}

// ---- GEMM + fused BN/ELU on input + fused alpha via extra MFMA ----
// Hb(bf16) = elu(bn(Xf)) @ W ; AS/AD = same A @ WA
__global__ __launch_bounds__(256) void k_gemm(const float* __restrict__ Xf,
                                              const float* __restrict__ stats,   // null if !apply_bn
                                              const float* __restrict__ gamma,
                                              const float* __restrict__ beta,
                                              const __hip_bfloat16* __restrict__ Wt,
                                              const __hip_bfloat16* __restrict__ WAT,
                                              __hip_bfloat16* __restrict__ Hb,
                                              float* __restrict__ AS, float* __restrict__ AD,
                                              int n_nodes, int apply_bn) {
    __shared__ float s_scale[128], s_shift[128];
    if (apply_bn && threadIdx.x < 128) {
        int c = threadIdx.x;
        float invN = 1.0f / (float)N_NODES;
        float mu = stats[c] * invN;
        float var = stats[128 + c] * invN - mu * mu;
        float sc = rsqrtf(var + BN_EPS) * gamma[c];
        s_scale[c] = sc;
        s_shift[c] = beta[c] - mu * sc;
    }
    __syncthreads();

    int wave = threadIdx.x >> 6, lane = threadIdx.x & 63;
    int row0 = blockIdx.x * 64 + wave * 16;
    int m_lane = lane & 15, kq = lane >> 4;
    floatx4 acc[8] = {};
    floatx4 acc_a = {};
    const short* Ws = (const short*)Wt;
    const short* Was = (const short*)WAT;
    int r = row0 + m_lane;
    int rr = (r < n_nodes) ? r : 0;
    for (int c = 0; c < 4; c++) {
        const float4* xp = (const float4*)(Xf + (size_t)rr * 128 + c * 32 + kq * 8);
        float4 v0 = xp[0], v1 = xp[1];
        float vals[8] = {v0.x, v0.y, v0.z, v0.w, v1.x, v1.y, v1.z, v1.w};
        short8 a;
        if (apply_bn) {
            int ch0 = c * 32 + kq * 8;
#pragma unroll
            for (int j = 0; j < 8; j++) {
                float val = fmaf(vals[j], s_scale[ch0 + j], s_shift[ch0 + j]);
                val = (val > 0.f) ? val : (__expf(val) - 1.0f);
                a[j] = f2bfs(val);
            }
        } else {
#pragma unroll
            for (int j = 0; j < 8; j++)
                a[j] = f2bfs(vals[j]);
        }
        for (int t = 0; t < 8; t++) {
            short8 b = *(const short8*)(Ws + (t * 16 + m_lane) * 128 + c * 32 + kq * 8);
            acc[t] = __builtin_amdgcn_mfma_f32_16x16x32_bf16(a, b, acc[t], 0, 0, 0);
        }
        short8 bwa = *(const short8*)(Was + m_lane * 128 + c * 32 + kq * 8);
        acc_a = __builtin_amdgcn_mfma_f32_16x16x32_bf16(a, bwa, acc_a, 0, 0, 0);
    }
#pragma unroll
    for (int reg = 0; reg < 4; reg++) {
        int row = row0 + kq * 4 + reg;
        if (row >= n_nodes) continue;
#pragma unroll
        for (int t = 0; t < 8; t++)
            Hb[(size_t)row * 128 + t * 16 + m_lane] = __float2bfloat16(acc[t][reg]);
        float av = acc_a[reg];
        if (m_lane < 8) AS[row * 8 + m_lane] = av;
        else            AD[row * 8 + (m_lane - 8)] = av;
    }
}

// ---- segment softmax + aggregation: one WAVE per node; lane = e_local*8 + head ----
__global__ __launch_bounds__(256) void k_agg(const int* __restrict__ RP,
                                             const int* __restrict__ COL,
                                             const float* __restrict__ AS,
                                             const float* __restrict__ AD,
                                             const __hip_bfloat16* __restrict__ Hb,
                                             const float* __restrict__ bias,
                                             float* __restrict__ out, int n_nodes) {
    int wave = threadIdx.x >> 6, lane = threadIdx.x & 63;
    int n = blockIdx.x * 4 + wave;
    if (n >= n_nodes) return;
    int e_l = lane >> 3, h = lane & 7;
    int p0 = RP[n], p1 = RP[n + 1];
    float ad = AD[n * 8 + h];
    float z = 0.f;
    float acc[16];
#pragma unroll
    for (int c = 0; c < 16; c++) acc[c] = 0.f;
    const unsigned short* Hu = (const unsigned short*)Hb;
    for (int p = p0 + e_l; p < p1; p += 8) {
        int s = COL[p];
        float e = AS[s * 8 + h] + ad;
        e = (e > 0.f) ? e : NEG_SLOPE * e;
        float w = __expf(e);   // no max-subtract: |e| << 80, safe in fp32
        z += w;
        const uint4* hp = (const uint4*)(Hu + (size_t)s * 128 + h * 16);
        uint4 h0 = hp[0];
        uint4 h1 = hp[1];
        unsigned int ww[8] = {h0.x, h0.y, h0.z, h0.w, h1.x, h1.y, h1.z, h1.w};
#pragma unroll
        for (int j = 0; j < 8; j++) {
            acc[2 * j]     += w * bf_lo(ww[j]);
            acc[2 * j + 1] += w * bf_hi(ww[j]);
        }
    }
    // plain butterfly sum over the 8 edge-lanes (lane bits 3..5)
#pragma unroll
    for (int off = 8; off < 64; off <<= 1) {
        z += __shfl_xor(z, off, 64);
#pragma unroll
        for (int c = 0; c < 16; c++) acc[c] += __shfl_xor(acc[c], off, 64);
    }
    if (e_l == 0) {
        float inv = 1.0f / (z + 1e-16f);
        float4* op = (float4*)(out + (size_t)n * 128 + h * 16);
        const float* bp = bias + h * 16;
#pragma unroll
        for (int q = 0; q < 4; q++) {
            op[q] = make_float4(acc[4 * q]     * inv + bp[4 * q],
                                acc[4 * q + 1] * inv + bp[4 * q + 1],
                                acc[4 * q + 2] * inv + bp[4 * q + 2],
                                acc[4 * q + 3] * inv + bp[4 * q + 3]);
        }
    }
}

// ---------------- BN stats (sum, sumsq per channel), float4 ----------------
__global__ void k_bnstats(const float* __restrict__ x, float* __restrict__ stats, int n_nodes) {
    int t = blockIdx.x * 256 + threadIdx.x;   // 65536 threads
    int c4 = t & 31;                           // float4 index in row
    int g = t >> 5;                            // 2048 groups
    float sx = 0.f, sy = 0.f, sz = 0.f, sw = 0.f;
    float qx = 0.f, qy = 0.f, qz = 0.f, qw = 0.f;
    for (int n = g; n < n_nodes; n += 2048) {
        float4 v = *(const float4*)(x + (size_t)n * 128 + c4 * 4);
        sx += v.x; sy += v.y; sz += v.z; sw += v.w;
        qx += v.x * v.x; qy += v.y * v.y; qz += v.z * v.z; qw += v.w * v.w;
    }
    int c = c4 * 4;
    atomicAdd(&stats[c + 0], sx);
    atomicAdd(&stats[c + 1], sy);
    atomicAdd(&stats[c + 2], sz);
    atomicAdd(&stats[c + 3], sw);
    atomicAdd(&stats[128 + c + 0], qx);
    atomicAdd(&stats[128 + c + 1], qy);
    atomicAdd(&stats[128 + c + 2], qz);
    atomicAdd(&stats[128 + c + 3], qw);
}

// ---------------- final BN apply + ELU -> fp32 out ----------------
__global__ void k_bnapply(const float* __restrict__ x, const float* __restrict__ stats,
                          const float* __restrict__ gamma, const float* __restrict__ beta,
                          float* __restrict__ outf, int n_nodes) {
    int i = blockIdx.x * 256 + threadIdx.x;   // each handles 4 channels
    if (i >= n_nodes * 32) return;
    float4 v = *(const float4*)(x + (size_t)i * 4);
    int c0 = (i * 4) & 127;
    float r[4] = {v.x, v.y, v.z, v.w};
    float invN = 1.0f / (float)N_NODES;
#pragma unroll
    for (int j = 0; j < 4; j++) {
        int c = c0 + j;
        float mu = stats[c] * invN;
        float var = stats[128 + c] * invN - mu * mu;
        float sc = rsqrtf(var + BN_EPS) * gamma[c];
        float val = (r[j] - mu) * sc + beta[c];
        val = (val > 0.f) ? val : (__expf(val) - 1.0f);
        r[j] = val;
    }
    *(float4*)(outf + (size_t)i * 4) = make_float4(r[0], r[1], r[2], r[3]);
}

extern "C" void kernel_launch(void* const* d_in, const int* in_sizes, int n_in,
                              void* d_out, int out_size, void* d_ws, size_t ws_size,
                              hipStream_t stream) {
    const float* x_in   = (const float*)d_in[0];
    const int*   eidx   = (const int*)d_in[1];
    const float* W      = (const float*)d_in[2];
    const float* attsrc = (const float*)d_in[3];
    const float* attdst = (const float*)d_in[4];
    const float* bias   = (const float*)d_in[5];
    const float* gamma  = (const float*)d_in[6];
    const float* beta   = (const float*)d_in[7];
    float* out = (float*)d_out;

    const int N = N_NODES, E = N_EDGES;
    const int* src = eidx;
    const int* dst = eidx + E;

    // workspace carve-up
    char* base = (char*)d_ws;
    size_t off = 0;
    auto carve = [&](size_t bytes) -> char* {
        char* p = base + off;
        off += (bytes + 255) & ~(size_t)255;
        return p;
    };
    __hip_bfloat16* Hb  = (__hip_bfloat16*)carve((size_t)N * HID * 2);
    float*          XN  = (float*)carve((size_t)N * HID * 4);
    float*          AS  = (float*)carve((size_t)N * HEADS * 4);
    float*          AD  = (float*)carve((size_t)N * HEADS * 4);
    __hip_bfloat16* WT  = (__hip_bfloat16*)carve((size_t)3 * HID * HID * 2);
    __hip_bfloat16* WAT = (__hip_bfloat16*)carve((size_t)3 * 16 * HID * 2);
    // STA (3 layers x 256 floats) and DEG carved adjacently -> single memset
    float*          STA = (float*)carve(3 * 256 * 4);          // 3072 B (multiple of 256)
    int*            DEG = (int*)carve((size_t)N * 4);
    int*            INC = (int*)carve((size_t)N * 4);
    int*            RP  = (int*)carve((size_t)(N + 1) * 4);
    int*            CUR = (int*)carve((size_t)N * 4);
    int*            PRT = (int*)carve(1024 * 4);
    int*            COL = (int*)carve((size_t)E * 4);

    const int NB_E  = (E + 255) / 256;
    const int NB_SC = (N + 511) / 512;   // 98

    // ---- single memset covers STA(3KB) + DEG ----
    (void)hipMemsetAsync(STA, 0, 3 * 256 * 4 + (size_t)N * 4, stream);

    // ---- CSR build (once; reused by all 3 layers) ----
    k_hist<<<NB_E, 256, 0, stream>>>(dst, DEG, E);
    k_scan1<<<NB_SC, 512, 0, stream>>>(DEG, INC, PRT, N);
    k_scan2<<<1, 128, 0, stream>>>(PRT, NB_SC);
    k_scan3<<<NB_SC, 512, 0, stream>>>(DEG, INC, PRT, RP, CUR, N, E);
    k_scatter<<<NB_E, 256, 0, stream>>>(src, dst, CUR, COL, E);

    // ---- weights: Wt bf16 transposed; WA = W folded with att vectors ----
    k_wt<<<(3 * 16384 + 255) / 256, 256, 0, stream>>>(W, WT);
    k_wa<<<(3 * 2048 + 255) / 256, 256, 0, stream>>>(W, attsrc, attdst, WAT);

    for (int l = 0; l < 3; l++) {
        const float* Xf = (l == 0) ? x_in : XN;
        const float* st = (l == 0) ? nullptr : (STA + (l - 1) * 256);
        const float* gm = gamma + (l - 1) * 128;   // unused when l==0
        const float* bt = beta + (l - 1) * 128;
        k_gemm<<<(N + 63) / 64, 256, 0, stream>>>(Xf, st, gm, bt,
                                                  WT + l * 16384, WAT + l * 2048,
                                                  Hb, AS, AD, N, (l == 0) ? 0 : 1);
        k_agg<<<(N + 3) / 4, 256, 0, stream>>>(RP, COL, AS, AD, Hb, bias + l * 128, XN, N);
        k_bnstats<<<256, 256, 0, stream>>>(XN, STA + l * 256, N);
    }
    k_bnapply<<<(N * 32 + 255) / 256, 256, 0, stream>>>(XN, STA + 2 * 256,
                                                        gamma + 2 * 128, beta + 2 * 128, out, N);
}

// Round 6
// 387.047 us; speedup vs baseline: 2.5424x; 2.5424x over previous
//
#include <hip/hip_runtime.h>
#include <hip/hip_bf16.h>

#define N_NODES 50000
#define N_EDGES 600000
#define HID 128
#define HEADS 8
#define OUTC 16
#define NEG_SLOPE 0.2f
#define BN_EPS 1e-5f

typedef __attribute__((ext_vector_type(8))) short short8;
typedef __attribute__((ext_vector_type(4))) float floatx4;

__device__ __forceinline__ float bf_lo(unsigned int v) { return __uint_as_float(v << 16); }
__device__ __forceinline__ float bf_hi(unsigned int v) { return __uint_as_float(v & 0xffff0000u); }

__device__ __forceinline__ short f2bfs(float v) {
    __hip_bfloat16 b = __float2bfloat16(v);
    return *reinterpret_cast<short*>(&b);
}

// ---------------- CSR build ----------------
__global__ void k_hist(const int* __restrict__ dst, int* __restrict__ deg, int e) {
    int i = blockIdx.x * 256 + threadIdx.x;
    if (i < e) atomicAdd(&deg[dst[i]], 1);
}

__global__ void k_scan1(const int* __restrict__ deg, int* __restrict__ incl,
                        int* __restrict__ partials, int n) {
    __shared__ int sh[512];
    int i = blockIdx.x * 512 + threadIdx.x;
    int v = (i < n) ? deg[i] : 0;
    sh[threadIdx.x] = v;
    __syncthreads();
    for (int off = 1; off < 512; off <<= 1) {
        int t = (threadIdx.x >= off) ? sh[threadIdx.x - off] : 0;
        __syncthreads();
        sh[threadIdx.x] += t;
        __syncthreads();
    }
    if (i < n) incl[i] = sh[threadIdx.x];
    if (threadIdx.x == 511) partials[blockIdx.x] = sh[511];
}

__global__ void k_scan2(int* __restrict__ partials, int nb) {
    __shared__ int sh[128];
    int v = (threadIdx.x < nb) ? partials[threadIdx.x] : 0;
    sh[threadIdx.x] = v;
    __syncthreads();
    for (int off = 1; off < 128; off <<= 1) {
        int t = (threadIdx.x >= off) ? sh[threadIdx.x - off] : 0;
        __syncthreads();
        sh[threadIdx.x] += t;
        __syncthreads();
    }
    if (threadIdx.x < nb) partials[threadIdx.x] = sh[threadIdx.x] - v;  // exclusive
}

__global__ void k_scan3(const int* __restrict__ deg, const int* __restrict__ incl,
                        const int* __restrict__ partials, int* __restrict__ row_ptr,
                        int* __restrict__ cursor, int n, int e_total) {
    int i = blockIdx.x * 512 + threadIdx.x;
    if (i < n) {
        int rp = incl[i] - deg[i] + partials[blockIdx.x];
        row_ptr[i] = rp;
        cursor[i] = rp;
    }
    if (i == 0) row_ptr[n] = e_total;
}

__global__ void k_scatter(const int* __restrict__ src, const int* __restrict__ dst,
                          int* __restrict__ cursor, int* __restrict__ col_src, int e) {
    int i = blockIdx.x * 256 + threadIdx.x;
    if (i < e) {
        int d = dst[i];
        int p = atomicAdd(&cursor[d], 1);
        col_src[p] = src[i];
    }
}

// ---------------- W fp32 -> bf16 transpose (Wt[l][n][k] = W[l][k][n]) ----------------
__global__ void k_wt(const float* __restrict__ W, __hip_bfloat16* __restrict__ Wt) {
    int i = blockIdx.x * 256 + threadIdx.x;   // 3*16384 total
    if (i >= 3 * 16384) return;
    int l = i >> 14, r = i & 16383, n = r >> 7, k = r & 127;
    Wt[i] = __float2bfloat16(W[l * 16384 + k * 128 + n]);
}

// -------- WA[l][j][k] = sum_c W[l][k][(j&7)*16+c] * att_j[c]  (j<8: src, j>=8: dst) ----
__global__ void k_wa(const float* __restrict__ W, const float* __restrict__ asrc,
                     const float* __restrict__ adst, __hip_bfloat16* __restrict__ WAT) {
    int i = blockIdx.x * 256 + threadIdx.x;   // 3*16*128 = 6144
    if (i >= 3 * 2048) return;
    int l = i >> 11, r = i & 2047, j = r >> 7, k = r & 127;
    const float* att = (j < 8) ? (asrc + l * 128 + j * 16) : (adst + l * 128 + (j - 8) * 16);
    const float* Wrow = W + l * 16384 + k * 128 + (j & 7) * 16;
    float sum = 0.f;
#pragma unroll
    for (int c = 0; c < 16; c++) sum += Wrow[c] * att[c];
    WAT[i] = __float2bfloat16(sum);
}

// ---- GEMM + fused BN/ELU on input + fused alpha via extra MFMA ----
// Hb(bf16) = elu(bn(Xf)) @ W ; AS/AD = same A @ WA
__global__ __launch_bounds__(256) void k_gemm(const float* __restrict__ Xf,
                                              const float* __restrict__ stats,   // null if !apply_bn
                                              const float* __restrict__ gamma,
                                              const float* __restrict__ beta,
                                              const __hip_bfloat16* __restrict__ Wt,
                                              const __hip_bfloat16* __restrict__ WAT,
                                              __hip_bfloat16* __restrict__ Hb,
                                              float* __restrict__ AS, float* __restrict__ AD,
                                              int n_nodes, int apply_bn) {
    __shared__ float s_scale[128], s_shift[128];
    if (apply_bn && threadIdx.x < 128) {
        int c = threadIdx.x;
        float invN = 1.0f / (float)N_NODES;
        float mu = stats[c] * invN;
        float var = stats[128 + c] * invN - mu * mu;
        float sc = rsqrtf(var + BN_EPS) * gamma[c];
        s_scale[c] = sc;
        s_shift[c] = beta[c] - mu * sc;
    }
    __syncthreads();

    int wave = threadIdx.x >> 6, lane = threadIdx.x & 63;
    int row0 = blockIdx.x * 64 + wave * 16;
    int m_lane = lane & 15, kq = lane >> 4;
    floatx4 acc[8] = {};
    floatx4 acc_a = {};
    const short* Ws = (const short*)Wt;
    const short* Was = (const short*)WAT;
    int r = row0 + m_lane;
    int rr = (r < n_nodes) ? r : 0;
    for (int c = 0; c < 4; c++) {
        const float4* xp = (const float4*)(Xf + (size_t)rr * 128 + c * 32 + kq * 8);
        float4 v0 = xp[0], v1 = xp[1];
        float vals[8] = {v0.x, v0.y, v0.z, v0.w, v1.x, v1.y, v1.z, v1.w};
        short8 a;
        if (apply_bn) {
            int ch0 = c * 32 + kq * 8;
#pragma unroll
            for (int j = 0; j < 8; j++) {
                float val = fmaf(vals[j], s_scale[ch0 + j], s_shift[ch0 + j]);
                val = (val > 0.f) ? val : (__expf(val) - 1.0f);
                a[j] = f2bfs(val);
            }
        } else {
#pragma unroll
            for (int j = 0; j < 8; j++)
                a[j] = f2bfs(vals[j]);
        }
        for (int t = 0; t < 8; t++) {
            short8 b = *(const short8*)(Ws + (t * 16 + m_lane) * 128 + c * 32 + kq * 8);
            acc[t] = __builtin_amdgcn_mfma_f32_16x16x32_bf16(a, b, acc[t], 0, 0, 0);
        }
        short8 bwa = *(const short8*)(Was + m_lane * 128 + c * 32 + kq * 8);
        acc_a = __builtin_amdgcn_mfma_f32_16x16x32_bf16(a, bwa, acc_a, 0, 0, 0);
    }
#pragma unroll
    for (int reg = 0; reg < 4; reg++) {
        int row = row0 + kq * 4 + reg;
        if (row >= n_nodes) continue;
#pragma unroll
        for (int t = 0; t < 8; t++)
            Hb[(size_t)row * 128 + t * 16 + m_lane] = __float2bfloat16(acc[t][reg]);
        float av = acc_a[reg];
        if (m_lane < 8) AS[row * 8 + m_lane] = av;
        else            AD[row * 8 + (m_lane - 8)] = av;
    }
}

// ---- segment softmax + aggregation: one WAVE per node; lane = e_local*8 + head ----
__global__ __launch_bounds__(256) void k_agg(const int* __restrict__ RP,
                                             const int* __restrict__ COL,
                                             const float* __restrict__ AS,
                                             const float* __restrict__ AD,
                                             const __hip_bfloat16* __restrict__ Hb,
                                             const float* __restrict__ bias,
                                             float* __restrict__ out, int n_nodes) {
    int wave = threadIdx.x >> 6, lane = threadIdx.x & 63;
    int n = blockIdx.x * 4 + wave;
    if (n >= n_nodes) return;
    int e_l = lane >> 3, h = lane & 7;
    int p0 = RP[n], p1 = RP[n + 1];
    float ad = AD[n * 8 + h];
    float z = 0.f;
    float acc[16];
#pragma unroll
    for (int c = 0; c < 16; c++) acc[c] = 0.f;
    const unsigned short* Hu = (const unsigned short*)Hb;
    for (int p = p0 + e_l; p < p1; p += 8) {
        int s = COL[p];
        float e = AS[s * 8 + h] + ad;
        e = (e > 0.f) ? e : NEG_SLOPE * e;
        float w = __expf(e);   // no max-subtract: |e| << 80, safe in fp32
        z += w;
        const uint4* hp = (const uint4*)(Hu + (size_t)s * 128 + h * 16);
        uint4 h0 = hp[0];
        uint4 h1 = hp[1];
        unsigned int ww[8] = {h0.x, h0.y, h0.z, h0.w, h1.x, h1.y, h1.z, h1.w};
#pragma unroll
        for (int j = 0; j < 8; j++) {
            acc[2 * j]     += w * bf_lo(ww[j]);
            acc[2 * j + 1] += w * bf_hi(ww[j]);
        }
    }
    // plain butterfly sum over the 8 edge-lanes (lane bits 3..5)
#pragma unroll
    for (int off = 8; off < 64; off <<= 1) {
        z += __shfl_xor(z, off, 64);
#pragma unroll
        for (int c = 0; c < 16; c++) acc[c] += __shfl_xor(acc[c], off, 64);
    }
    if (e_l == 0) {
        float inv = 1.0f / (z + 1e-16f);
        float4* op = (float4*)(out + (size_t)n * 128 + h * 16);
        const float* bp = bias + h * 16;
#pragma unroll
        for (int q = 0; q < 4; q++) {
            op[q] = make_float4(acc[4 * q]     * inv + bp[4 * q],
                                acc[4 * q + 1] * inv + bp[4 * q + 1],
                                acc[4 * q + 2] * inv + bp[4 * q + 2],
                                acc[4 * q + 3] * inv + bp[4 * q + 3]);
        }
    }
}

// ---- BN stats stage A: per-block partials (NO atomics) ----
// 256 blocks x 256 thr; partials[b][0..127]=sum, [128..255]=sumsq
__global__ __launch_bounds__(256) void k_bnstats(const float* __restrict__ x,
                                                 float* __restrict__ partials, int n_nodes) {
    int tid = threadIdx.x;
    int c4 = tid & 31, sub = tid >> 5;          // 8 row-groups per block
    int g = blockIdx.x * 8 + sub;               // 2048 row-groups total
    float sx = 0.f, sy = 0.f, sz = 0.f, sw = 0.f;
    float qx = 0.f, qy = 0.f, qz = 0.f, qw = 0.f;
    for (int n = g; n < n_nodes; n += 2048) {
        float4 v = *(const float4*)(x + (size_t)n * 128 + c4 * 4);
        sx += v.x; sy += v.y; sz += v.z; sw += v.w;
        qx += v.x * v.x; qy += v.y * v.y; qz += v.z * v.z; qw += v.w * v.w;
    }
    __shared__ float ssum[8][128];
    __shared__ float ssq[8][128];
    int c = c4 * 4;
    ssum[sub][c] = sx; ssum[sub][c + 1] = sy; ssum[sub][c + 2] = sz; ssum[sub][c + 3] = sw;
    ssq[sub][c] = qx;  ssq[sub][c + 1] = qy;  ssq[sub][c + 2] = qz;  ssq[sub][c + 3] = qw;
    __syncthreads();
    float total = 0.f;
    if (tid < 128) {
#pragma unroll
        for (int k = 0; k < 8; k++) total += ssum[k][tid];
    } else {
        int cc = tid - 128;
#pragma unroll
        for (int k = 0; k < 8; k++) total += ssq[k][cc];
    }
    partials[blockIdx.x * 256 + tid] = total;
}

// ---- BN stats stage B: reduce 256 partial rows -> stats[256] ----
__global__ void k_bnreduce(const float* __restrict__ partials, float* __restrict__ stats) {
    int t = threadIdx.x;   // 256
    float s = 0.f;
#pragma unroll 8
    for (int b = 0; b < 256; b++) s += partials[b * 256 + t];
    stats[t] = s;
}

// ---------------- final BN apply + ELU -> fp32 out ----------------
__global__ void k_bnapply(const float* __restrict__ x, const float* __restrict__ stats,
                          const float* __restrict__ gamma, const float* __restrict__ beta,
                          float* __restrict__ outf, int n_nodes) {
    int i = blockIdx.x * 256 + threadIdx.x;   // each handles 4 channels
    if (i >= n_nodes * 32) return;
    float4 v = *(const float4*)(x + (size_t)i * 4);
    int c0 = (i * 4) & 127;
    float r[4] = {v.x, v.y, v.z, v.w};
    float invN = 1.0f / (float)N_NODES;
#pragma unroll
    for (int j = 0; j < 4; j++) {
        int c = c0 + j;
        float mu = stats[c] * invN;
        float var = stats[128 + c] * invN - mu * mu;
        float sc = rsqrtf(var + BN_EPS) * gamma[c];
        float val = (r[j] - mu) * sc + beta[c];
        val = (val > 0.f) ? val : (__expf(val) - 1.0f);
        r[j] = val;
    }
    *(float4*)(outf + (size_t)i * 4) = make_float4(r[0], r[1], r[2], r[3]);
}

extern "C" void kernel_launch(void* const* d_in, const int* in_sizes, int n_in,
                              void* d_out, int out_size, void* d_ws, size_t ws_size,
                              hipStream_t stream) {
    const float* x_in   = (const float*)d_in[0];
    const int*   eidx   = (const int*)d_in[1];
    const float* W      = (const float*)d_in[2];
    const float* attsrc = (const float*)d_in[3];
    const float* attdst = (const float*)d_in[4];
    const float* bias   = (const float*)d_in[5];
    const float* gamma  = (const float*)d_in[6];
    const float* beta   = (const float*)d_in[7];
    float* out = (float*)d_out;

    const int N = N_NODES, E = N_EDGES;
    const int* src = eidx;
    const int* dst = eidx + E;

    // workspace carve-up
    char* base = (char*)d_ws;
    size_t off = 0;
    auto carve = [&](size_t bytes) -> char* {
        char* p = base + off;
        off += (bytes + 255) & ~(size_t)255;
        return p;
    };
    __hip_bfloat16* Hb  = (__hip_bfloat16*)carve((size_t)N * HID * 2);
    float*          XN  = (float*)carve((size_t)N * HID * 4);
    float*          AS  = (float*)carve((size_t)N * HEADS * 4);
    float*          AD  = (float*)carve((size_t)N * HEADS * 4);
    __hip_bfloat16* WT  = (__hip_bfloat16*)carve((size_t)3 * HID * HID * 2);
    __hip_bfloat16* WAT = (__hip_bfloat16*)carve((size_t)3 * 16 * HID * 2);
    float*          STA = (float*)carve(3 * 256 * 4);
    float*          PAR = (float*)carve(256 * 256 * 4);       // bnstats partials
    int*            DEG = (int*)carve((size_t)N * 4);
    int*            INC = (int*)carve((size_t)N * 4);
    int*            RP  = (int*)carve((size_t)(N + 1) * 4);
    int*            CUR = (int*)carve((size_t)N * 4);
    int*            PRT = (int*)carve(1024 * 4);
    int*            COL = (int*)carve((size_t)E * 4);

    const int NB_E  = (E + 255) / 256;
    const int NB_SC = (N + 511) / 512;   // 98

    // ---- memset covers DEG only (STA is overwritten by k_bnreduce) ----
    (void)hipMemsetAsync(DEG, 0, (size_t)N * 4, stream);

    // ---- CSR build (once; reused by all 3 layers) ----
    k_hist<<<NB_E, 256, 0, stream>>>(dst, DEG, E);
    k_scan1<<<NB_SC, 512, 0, stream>>>(DEG, INC, PRT, N);
    k_scan2<<<1, 128, 0, stream>>>(PRT, NB_SC);
    k_scan3<<<NB_SC, 512, 0, stream>>>(DEG, INC, PRT, RP, CUR, N, E);
    k_scatter<<<NB_E, 256, 0, stream>>>(src, dst, CUR, COL, E);

    // ---- weights: Wt bf16 transposed; WA = W folded with att vectors ----
    k_wt<<<(3 * 16384 + 255) / 256, 256, 0, stream>>>(W, WT);
    k_wa<<<(3 * 2048 + 255) / 256, 256, 0, stream>>>(W, attsrc, attdst, WAT);

    for (int l = 0; l < 3; l++) {
        const float* Xf = (l == 0) ? x_in : XN;
        const float* st = (l == 0) ? nullptr : (STA + (l - 1) * 256);
        const float* gm = gamma + (l - 1) * 128;   // unused when l==0
        const float* bt = beta + (l - 1) * 128;
        k_gemm<<<(N + 63) / 64, 256, 0, stream>>>(Xf, st, gm, bt,
                                                  WT + l * 16384, WAT + l * 2048,
                                                  Hb, AS, AD, N, (l == 0) ? 0 : 1);
        k_agg<<<(N + 3) / 4, 256, 0, stream>>>(RP, COL, AS, AD, Hb, bias + l * 128, XN, N);
        k_bnstats<<<256, 256, 0, stream>>>(XN, PAR, N);
        k_bnreduce<<<1, 256, 0, stream>>>(PAR, STA + l * 256);
    }
    k_bnapply<<<(N * 32 + 255) / 256, 256, 0, stream>>>(XN, STA + 2 * 256,
                                                        gamma + 2 * 128, beta + 2 * 128, out, N);
}